// Round 8
// baseline (5554.390 us; speedup 1.0000x reference)
//
#include <hip/hip_runtime.h>
#include <stdint.h>

#define NBATCH 32
#define NPTS   65536
#define MCENT  2048
#define BPB    8                 // blocks per batch (R5 proven topology)
#define THREADS 1024
#define CHUNK  (NPTS / BPB)      // 8192 points per block
#define WPT    (CHUNK / THREADS) // 8 points per thread
#define NWAVE  (THREADS / 64)    // 16 waves
#define GPW    2                 // groups (half-waves) per wave
#define NGRP   (NWAVE * GPW)     // 32 groups per block (256 pts each)
#define TMAX   64                // max centers selected per sync round

typedef unsigned long long u64;
typedef uint32_t u32;

static __device__ __forceinline__ u32 fbits(float f) { union { float f; u32 u; } c; c.f = f; return c.u; }
static __device__ __forceinline__ float bitsf(u32 u) { union { u32 u; float f; } c; c.u = u; return c.f; }

// wave-wide max of nonneg u32 via DPP row reduce (proven R4/R5);
// bound_ctrl=true -> invalid sources read 0 (identity for nonneg max).
static __device__ __forceinline__ u32 wave_max_u32(u32 v) {
#define STEP(CTRL) { const u32 o = (u32)__builtin_amdgcn_update_dpp(0, (int)v, CTRL, 0xF, 0xF, true); v = o > v ? o : v; }
    STEP(0x111) // row_shr:1
    STEP(0x112) // row_shr:2
    STEP(0x114) // row_shr:4
    STEP(0x118) // row_shr:8
    STEP(0x142) // row_bcast15
    STEP(0x143) // row_bcast31
#undef STEP
    return (u32)__builtin_amdgcn_readlane((int)v, 63);
}

// Multi-step FPS with a published candidate pool (R5 protocol/topology,
// best proven 2055 us) + SLEEP-CONSUME overlap: while wave 0 runs the
// serial pool-FPS, waves 1..15 consume winners from tagged LDS slots as
// they are produced (Phase A overlapped with pool-FPS). R6's version of
// this regressed 2.4x because consumers HOT-SPUN (15 waves stealing
// issue/LDS bandwidth from wave 0's critical path); here consumers
// s_sleep(1) between checks (~13% residual issue pressure) and the
// single per-round barrier (R5 skeleton) is kept at loop end.
//
// Global pool protocol (proven R2..R7):
//   word = val_bits[63:32] | (idx^0xFFFF)[31:16] | sync_tag[15:0]
//   key order (val desc, idx asc) == jnp.argmax first-occurrence semantics.
//   Tags: poison 0xAA.. -> 0xAAAA, zero -> 0; s in [1,2047] never aliases.
//   Parity reuse safe (transitive): a block publishes s+1 only after all
//   its waves consumed round-s winners, which requires wave0's round-s
//   poll complete, which requires every peer published s, which requires
//   that peer banked its reads of round s-1 words. So overwriting
//   parity-(s&1) words at round s+2 is safe.
//
// LDS winner protocol (correctness proven by R6 — it passed, only slow):
//   slot tt: {wsx,wsy,wsz}[tt], threadfence_block, wstag[tt]=s.
//   After last winner: threadfence_block, wtn=(s<<8)|count.
//   Sentinel-init 0xFFFFFFFF matches no round. If wtn shows round s,
//   all round-s slot tags are already visible (fenced before wtn).
//
// Exactness: winner sequence, distance chain (subs, then
// fma(dz,dz, fma(dx,dx, mul(dy,dy))), chronological fminf order), tau
// rule (accept iff value strictly > max of group TOPK-th values) and
// first-occurrence tie-breaks are bit-identical to verified R5.
// Consumers apply winners in slot order == R5's loop order.

template<int TOPK>
__global__ __launch_bounds__(THREADS, 1) void fps_kernel(
    const float* __restrict__ xyz,      // [NBATCH, NPTS, 3] fp32
    float* __restrict__ out,            // [NBATCH, MCENT, 3] fp32
    u64* __restrict__ slots)
{
    constexpr int POOLW = BPB * NGRP * TOPK;   // words per batch per parity
    constexpr int WPL   = POOLW / 64;          // words per lane (wave 0)

    const int t = threadIdx.x;
    const int b = blockIdx.x >> 3;   // batch (proven mapping)
    const int j = blockIdx.x & 7;    // block-within-batch
    const float* base = xyz + (size_t)b * NPTS * 3;
    const int p0 = j * CHUNK;
    const int wave = t >> 6;
    const int lane = t & 63;

    // coords + running min-dist live in registers
    float px[WPT], py[WPT], pz[WPT], pd[WPT];
#pragma unroll
    for (int q = 0; q < WPT; ++q) {
        const int p = p0 + q * THREADS + t;
        px[q] = base[(size_t)p * 3 + 0];
        py[q] = base[(size_t)p * 3 + 1];
        pz[q] = base[(size_t)p * 3 + 2];
        pd[q] = 1e10f;
    }

    // tagged LDS winner slots (R6-proven protocol)
    __shared__ volatile float wsx[TMAX], wsy[TMAX], wsz[TMAX];
    __shared__ volatile u32   wstag[TMAX];
    __shared__ volatile u32   wtn;     // (round<<8) | count

    if (t < TMAX) wstag[t] = 0xFFFFFFFFu;   // matches no round
    if (t == 0) {
        wtn = 0xFFFFFFFFu;
        if (j == 0) {
            float* o = out + (size_t)b * MCENT * 3;
            o[0] = base[0]; o[1] = base[1]; o[2] = base[2];
        }
    }
    __syncthreads();   // init visibility

    // initial center applied by ALL waves directly from registers
    {
        const float cx = base[0], cy = base[1], cz = base[2];
#pragma unroll
        for (int q = 0; q < WPT; ++q) {
            const float dx = __fsub_rn(px[q], cx);
            const float dy = __fsub_rn(py[q], cy);
            const float dz = __fsub_rn(pz[q], cz);
            const float s2 = __fmaf_rn(dz, dz,
                             __fmaf_rn(dx, dx,
                             __fmul_rn(dy, dy)));
            pd[q] = fminf(pd[q], s2);
        }
    }

    int C = 1;  // centers accounted (uniform across all waves/blocks)
    for (int s = 1; ; ++s) {
        // ---- per-lane top-TOPK keys over its 8 points (sorted insert) ----
        u64 k1 = 0, k2 = 0, k3 = 0;
#pragma unroll
        for (int q = 0; q < WPT; ++q) {
            const u64 kk = ((u64)fbits(pd[q]) << 16)
                         | (u64)(0xFFFFu ^ (u32)(p0 + q * THREADS + t));
            if (kk > k1)      { k3 = k2; k2 = k1; k1 = kk; }
            else if (kk > k2) { k3 = k2; k2 = kk; }
            else if (kk > k3) { k3 = kk; }
        }
        // ---- half-wave top-TOPK butterfly (5 xor levels, 32 lanes) ----
#pragma unroll
        for (int m = 1; m <= 16; m <<= 1) {
            const u64 o1 = __shfl_xor(k1, m);
            const u64 o2 = __shfl_xor(k2, m);
            if constexpr (TOPK == 2) {
                if (o1 > k1) { k2 = (k1 > o2) ? k1 : o2; k1 = o1; }
                else         { k2 = (k2 > o1) ? k2 : o1; }
            } else {
                const u64 o3 = __shfl_xor(k3, m);
                // merge sorted triples (k1>=k2>=k3), (o1>=o2>=o3) -> top-3
                u64 m1, m2, m3;
                if (o1 > k1) {
                    m1 = o1;
                    if (o2 > k1) { m2 = o2; m3 = (o3 > k1) ? o3 : k1; }
                    else         { m2 = k1; m3 = (o2 > k2) ? o2 : k2; }
                } else {
                    m1 = k1;
                    if (o1 > k2) { m2 = o1; m3 = (o2 > k2) ? o2 : k2; }
                    else         { m2 = k2; m3 = (o1 > k3) ? o1 : k3; }
                }
                k1 = m1; k2 = m2; k3 = m3;
            }
        }

        u64* const bb = slots + ((size_t)(s & 1) * NBATCH + b) * POOLW;
        const u32 tag = (u32)s & 0xFFFFu;

        // ---- publish: first lane of each half-wave stores TOPK words ----
        if ((lane & 31) == 0) {
            const int g = wave * GPW + (lane >> 5);     // group id 0..NGRP-1
            u64* const gw = &bb[j * (NGRP * TOPK) + g * TOPK];
            __hip_atomic_store(&gw[0], (k1 << 16) | tag,
                               __ATOMIC_RELAXED, __HIP_MEMORY_SCOPE_AGENT);
            __hip_atomic_store(&gw[1], (k2 << 16) | tag,
                               __ATOMIC_RELAXED, __HIP_MEMORY_SCOPE_AGENT);
            if constexpr (TOPK == 3)
                __hip_atomic_store(&gw[2], (k3 << 16) | tag,
                                   __ATOMIC_RELAXED, __HIP_MEMORY_SCOPE_AGENT);
        }

        int tn;   // winners this round (uniform by loop end)

        if (wave == 0) {
            // ---- poll: WPL coalesced words/lane until all carry tag s ----
            u64 w[WPL]; int ok;
            do {
#pragma unroll
                for (int r = 0; r < WPL; ++r)
                    w[r] = __hip_atomic_load(&bb[lane + 64 * r],
                                             __ATOMIC_RELAXED, __HIP_MEMORY_SCOPE_AGENT);
                ok = 1;
#pragma unroll
                for (int r = 0; r < WPL; ++r)
                    ok &= ((u32)(w[r] & 0xFFFFull) == tag);
            } while (!__all(ok));

            // ---- unpack pool: split (val, inv-idx) + gather coords ----
            u32 pv[WPL], pi[WPL];
            float ex[WPL], ey[WPL], ez[WPL];
#pragma unroll
            for (int r = 0; r < WPL; ++r) {
                pv[r] = (u32)(w[r] >> 32);
                pi[r] = ((u32)w[r] >> 16) & 0xFFFFu;
                const int gi = (int)(0xFFFFu ^ pi[r]);   // global point idx
                ex[r] = base[(size_t)gi * 3 + 0];
                ey[r] = base[(size_t)gi * 3 + 1];
                ez[r] = base[(size_t)gi * 3 + 2];
            }

            // tau = max over group-LAST (TOPK-th) entries. Word index is
            // lane + 64*r -> rank = (lane%TOPK + (64%TOPK)*r) % TOPK.
            u32 tl = 0;
#pragma unroll
            for (int r = 0; r < WPL; ++r) {
                const int rank = ((lane % TOPK) + (64 % TOPK) * r) % TOPK;
                if (rank == TOPK - 1) tl = pv[r] > tl ? pv[r] : tl;
            }
            const u32 tauv = wave_max_u32(tl);

            // ---- pool-FPS: exact multi-step selection + live broadcast ----
            int tc = 0;
            while (1) {
                u32 lv = 0;
#pragma unroll
                for (int r = 0; r < WPL; ++r) lv = pv[r] > lv ? pv[r] : lv;
                const u32 vmax = wave_max_u32(lv);
                // step >=2 valid only if winner VALUE strictly beats tau
                if (tc > 0 && vmax <= tauv) break;

                // per-lane best inv among entries matching vmax (0 = none)
                u32 ic = 0;
#pragma unroll
                for (int r = 0; r < WPL; ++r)
                    ic = (pv[r] == vmax && pi[r] + 1u > ic) ? pi[r] + 1u : ic;
                const u64 bal = __ballot(ic != 0);
                u32 winv; int ol;
                if (__popcll(bal) == 1) {
                    // single owner lane: local tie-break already in ic
                    ol = (int)__ffsll((long long)bal) - 1;
                    winv = __shfl(ic, ol) - 1u;
                } else {
                    // exact cross-lane tie-break: smallest global idx
                    winv = wave_max_u32(ic) - 1u;
                    int m = 0;
#pragma unroll
                    for (int r = 0; r < WPL; ++r)
                        m |= (pv[r] == vmax) & (pi[r] == winv);
                    ol = (int)__ffsll((long long)__ballot(m)) - 1;
                }

                // owner entry -> winner coords to all lanes
                float sx = 0.f, sy = 0.f, sz = 0.f;
#pragma unroll
                for (int r = 0; r < WPL; ++r) {
                    const int m = (pv[r] == vmax) & (pi[r] == winv);
                    sx = m ? ex[r] : sx;
                    sy = m ? ey[r] : sy;
                    sz = m ? ez[r] : sz;
                }
                const float wx = __shfl(sx, ol);
                const float wy = __shfl(sy, ol);
                const float wz = __shfl(sz, ol);

                // live broadcast: slot data, fence, tag
                if (lane == 0) {
                    wsx[tc] = wx; wsy[tc] = wy; wsz[tc] = wz;
                    __threadfence_block();
                    wstag[tc] = (u32)s;
                    if (j == 0) {
                        float* o = out + ((size_t)b * MCENT + (C + tc)) * 3;
                        o[0] = wx; o[1] = wy; o[2] = wz;
                    }
                }

                // inline update of wave 0's own points (same fminf order)
#pragma unroll
                for (int q = 0; q < WPT; ++q) {
                    const float dx = __fsub_rn(px[q], wx);
                    const float dy = __fsub_rn(py[q], wy);
                    const float dz = __fsub_rn(pz[q], wz);
                    const float s2 = __fmaf_rn(dz, dz,
                                     __fmaf_rn(dx, dx,
                                     __fmul_rn(dy, dy)));
                    pd[q] = fminf(pd[q], s2);
                }

                ++tc;
                if (C + tc >= MCENT || tc >= TMAX) break;

                // min-update all pool entries vs winner (bit-exact chain)
#pragma unroll
                for (int r = 0; r < WPL; ++r) {
                    const float dx = __fsub_rn(ex[r], wx);
                    const float dy = __fsub_rn(ey[r], wy);
                    const float dz = __fsub_rn(ez[r], wz);
                    const float s2 = __fmaf_rn(dz, dz,
                                     __fmaf_rn(dx, dx,
                                     __fmul_rn(dy, dy)));
                    pv[r] = fbits(fminf(bitsf(pv[r]), s2));
                }
            }
            if (lane == 0) {
                __threadfence_block();
                wtn = ((u32)s << 8) | (u32)tc;   // count, tagged with round
            }
            tn = tc;
        } else {
            // ---- sleep-consume: apply winners as they are produced ----
            int tt = 0, cnt = -1;
            while (cnt < 0 || tt < cnt) {
                if (tt < TMAX && wstag[tt] == (u32)s) {
                    const float cx = wsx[tt], cy = wsy[tt], cz = wsz[tt];
#pragma unroll
                    for (int q = 0; q < WPT; ++q) {
                        const float dx = __fsub_rn(px[q], cx);
                        const float dy = __fsub_rn(py[q], cy);
                        const float dz = __fsub_rn(pz[q], cz);
                        const float s2 = __fmaf_rn(dz, dz,
                                         __fmaf_rn(dx, dx,
                                         __fmul_rn(dy, dy)));
                        pd[q] = fminf(pd[q], s2);
                    }
                    ++tt;
                } else {
                    const u32 wd = wtn;
                    if ((wd >> 8) == (u32)s) cnt = (int)(wd & 0xFFu);
                    else __builtin_amdgcn_s_sleep(1);   // park ~64 cy
                }
            }
            tn = cnt;
        }

        C += tn;
        __syncthreads();        // single per-round barrier: aligns waves,
                                // guards LDS slot reuse for round s+1
        if (C >= MCENT) break;
    }
}

extern "C" void kernel_launch(void* const* d_in, const int* in_sizes, int n_in,
                              void* d_out, int out_size, void* d_ws, size_t ws_size,
                              hipStream_t stream) {
    const float* xyz = (const float*)d_in[0];
    float* out = (float*)d_out;
    u64* slots = (u64*)d_ws;

    // top-3 pool needs 2 parity x 32 batch x 768 words x 8 B = 384 KiB
    const size_t need3 = 2ull * NBATCH * (BPB * NGRP * 3) * sizeof(u64);
    if (ws_size >= need3) {
        fps_kernel<3><<<dim3(NBATCH * BPB), dim3(THREADS), 0, stream>>>(xyz, out, slots);
    } else {
        // TOPK=2 fallback (256 KiB)
        fps_kernel<2><<<dim3(NBATCH * BPB), dim3(THREADS), 0, stream>>>(xyz, out, slots);
    }
}

// Round 9
// 2340.687 us; speedup vs baseline: 2.3730x; 2.3730x over previous
//
#include <hip/hip_runtime.h>
#include <stdint.h>

#define NBATCH 32
#define NPTS   65536
#define MCENT  2048
#define BPB    8                 // blocks per batch (R5 proven topology)
#define THREADS 1024
#define CHUNK  (NPTS / BPB)      // 8192 points per block
#define WPT    (CHUNK / THREADS) // 8 points per thread
#define NWAVE  (THREADS / 64)    // 16 waves
#define GPW    2                 // groups (half-waves) per wave
#define NGRP   (NWAVE * GPW)     // 32 groups per block (256 pts each)
#define TMAX   64                // max centers selected per sync round

typedef unsigned long long u64;
typedef uint32_t u32;

static __device__ __forceinline__ u32 fbits(float f) { union { float f; u32 u; } c; c.f = f; return c.u; }
static __device__ __forceinline__ float bitsf(u32 u) { union { u32 u; float f; } c; c.u = u; return c.f; }

// wave-wide max of nonneg u32 via DPP row reduce (proven R4/R5);
// bound_ctrl=true -> invalid sources read 0 (identity for nonneg max).
static __device__ __forceinline__ u32 wave_max_u32(u32 v) {
#define STEP(CTRL) { const u32 o = (u32)__builtin_amdgcn_update_dpp(0, (int)v, CTRL, 0xF, 0xF, true); v = o > v ? o : v; }
    STEP(0x111) // row_shr:1
    STEP(0x112) // row_shr:2
    STEP(0x114) // row_shr:4
    STEP(0x118) // row_shr:8
    STEP(0x142) // row_bcast15
    STEP(0x143) // row_bcast31
#undef STEP
    return (u32)__builtin_amdgcn_readlane((int)v, 63);
}

// Multi-step FPS, R5 protocol/topology (best proven 2055 us) + sleep-consume
// overlap with the R8 FENCE BUG FIXED.
//
// R6/R8 post-mortem: their per-winner __threadfence_block() emits
// s_waitcnt vmcnt(0) — wave 0 of each j==0 block had an outstanding global
// `out` store per winner, so production serialized on global-store
// completion and every peer polled idle waiting for it (R8: +103 MB FETCH
// of extra poll spins). Fixes here:
//   (a) producer orders LDS data->tag with s_waitcnt lgkmcnt(0) ONLY
//       (LDS ops of a wave complete in order past it; never waits vmem);
//   (b) out-writes moved OUT of the winner loop (batched, one per lane);
//   (c) wave 0 does no inline pd update per winner; it applies winners
//       from LDS after releasing the count word (same slot order as
//       consumers == R5 Phase-A order -> bit-identical fminf chronology).
//
// Global pool protocol (proven R2..R8): word = val|invidx|tag, parity
// buffers, transitive reuse safety — see prior rounds. Exactness: winner
// sequence, distance chain (subs, then fma(dz,dz, fma(dx,dx, mul(dy,dy))),
// chronological fminf), tau rule (accept iff value strictly > max of group
// TOPK-th values), first-occurrence tie-breaks — bit-identical to R5.
//
// LDS winner protocol: slot tt: data, lgkmcnt(0), wstag[tt]=s; after last:
// lgkmcnt(0), wtn=(s<<8)|count. Sentinel 0xFFFFFFFF matches no round.
// Consumers s_sleep(1) between checks (~13% issue pressure vs hot spin).

template<int TOPK>
__global__ __launch_bounds__(THREADS, 1) void fps_kernel(
    const float* __restrict__ xyz,      // [NBATCH, NPTS, 3] fp32
    float* __restrict__ out,            // [NBATCH, MCENT, 3] fp32
    u64* __restrict__ slots)
{
    constexpr int POOLW = BPB * NGRP * TOPK;   // words per batch per parity
    constexpr int WPL   = POOLW / 64;          // words per lane (wave 0)

    const int t = threadIdx.x;
    const int b = blockIdx.x >> 3;   // batch (proven mapping)
    const int j = blockIdx.x & 7;    // block-within-batch
    const float* base = xyz + (size_t)b * NPTS * 3;
    const int p0 = j * CHUNK;
    const int wave = t >> 6;
    const int lane = t & 63;

    // coords + running min-dist live in registers
    float px[WPT], py[WPT], pz[WPT], pd[WPT];
#pragma unroll
    for (int q = 0; q < WPT; ++q) {
        const int p = p0 + q * THREADS + t;
        px[q] = base[(size_t)p * 3 + 0];
        py[q] = base[(size_t)p * 3 + 1];
        pz[q] = base[(size_t)p * 3 + 2];
        pd[q] = 1e10f;
    }

    // tagged LDS winner slots
    __shared__ volatile float wsx[TMAX], wsy[TMAX], wsz[TMAX];
    __shared__ volatile u32   wstag[TMAX];
    __shared__ volatile u32   wtn;     // (round<<8) | count

    if (t < TMAX) wstag[t] = 0xFFFFFFFFu;   // matches no round
    if (t == 0) {
        wtn = 0xFFFFFFFFu;
        if (j == 0) {
            float* o = out + (size_t)b * MCENT * 3;
            o[0] = base[0]; o[1] = base[1]; o[2] = base[2];
        }
    }
    __syncthreads();   // init visibility

    // initial center applied by ALL waves directly from registers
    {
        const float cx = base[0], cy = base[1], cz = base[2];
#pragma unroll
        for (int q = 0; q < WPT; ++q) {
            const float dx = __fsub_rn(px[q], cx);
            const float dy = __fsub_rn(py[q], cy);
            const float dz = __fsub_rn(pz[q], cz);
            const float s2 = __fmaf_rn(dz, dz,
                             __fmaf_rn(dx, dx,
                             __fmul_rn(dy, dy)));
            pd[q] = fminf(pd[q], s2);
        }
    }

    int C = 1;  // centers accounted (uniform across all waves/blocks)
    for (int s = 1; ; ++s) {
        // ---- per-lane top-TOPK keys over its 8 points (sorted insert) ----
        u64 k1 = 0, k2 = 0, k3 = 0;
#pragma unroll
        for (int q = 0; q < WPT; ++q) {
            const u64 kk = ((u64)fbits(pd[q]) << 16)
                         | (u64)(0xFFFFu ^ (u32)(p0 + q * THREADS + t));
            if (kk > k1)      { k3 = k2; k2 = k1; k1 = kk; }
            else if (kk > k2) { k3 = k2; k2 = kk; }
            else if (kk > k3) { k3 = kk; }
        }
        // ---- half-wave top-TOPK butterfly (5 xor levels, 32 lanes) ----
#pragma unroll
        for (int m = 1; m <= 16; m <<= 1) {
            const u64 o1 = __shfl_xor(k1, m);
            const u64 o2 = __shfl_xor(k2, m);
            if constexpr (TOPK == 2) {
                if (o1 > k1) { k2 = (k1 > o2) ? k1 : o2; k1 = o1; }
                else         { k2 = (k2 > o1) ? k2 : o1; }
            } else {
                const u64 o3 = __shfl_xor(k3, m);
                // merge sorted triples (k1>=k2>=k3), (o1>=o2>=o3) -> top-3
                u64 m1, m2, m3;
                if (o1 > k1) {
                    m1 = o1;
                    if (o2 > k1) { m2 = o2; m3 = (o3 > k1) ? o3 : k1; }
                    else         { m2 = k1; m3 = (o2 > k2) ? o2 : k2; }
                } else {
                    m1 = k1;
                    if (o1 > k2) { m2 = o1; m3 = (o2 > k2) ? o2 : k2; }
                    else         { m2 = k2; m3 = (o1 > k3) ? o1 : k3; }
                }
                k1 = m1; k2 = m2; k3 = m3;
            }
        }

        u64* const bb = slots + ((size_t)(s & 1) * NBATCH + b) * POOLW;
        const u32 tag = (u32)s & 0xFFFFu;

        // ---- publish: first lane of each half-wave stores TOPK words ----
        if ((lane & 31) == 0) {
            const int g = wave * GPW + (lane >> 5);     // group id 0..NGRP-1
            u64* const gw = &bb[j * (NGRP * TOPK) + g * TOPK];
            __hip_atomic_store(&gw[0], (k1 << 16) | tag,
                               __ATOMIC_RELAXED, __HIP_MEMORY_SCOPE_AGENT);
            __hip_atomic_store(&gw[1], (k2 << 16) | tag,
                               __ATOMIC_RELAXED, __HIP_MEMORY_SCOPE_AGENT);
            if constexpr (TOPK == 3)
                __hip_atomic_store(&gw[2], (k3 << 16) | tag,
                                   __ATOMIC_RELAXED, __HIP_MEMORY_SCOPE_AGENT);
        }

        int tn;   // winners this round (uniform by loop end)

        if (wave == 0) {
            // ---- poll: WPL coalesced words/lane until all carry tag s ----
            u64 w[WPL]; int ok;
            do {
#pragma unroll
                for (int r = 0; r < WPL; ++r)
                    w[r] = __hip_atomic_load(&bb[lane + 64 * r],
                                             __ATOMIC_RELAXED, __HIP_MEMORY_SCOPE_AGENT);
                ok = 1;
#pragma unroll
                for (int r = 0; r < WPL; ++r)
                    ok &= ((u32)(w[r] & 0xFFFFull) == tag);
            } while (!__all(ok));

            // ---- unpack pool: split (val, inv-idx) + gather coords ----
            u32 pv[WPL], pi[WPL];
            float ex[WPL], ey[WPL], ez[WPL];
#pragma unroll
            for (int r = 0; r < WPL; ++r) {
                pv[r] = (u32)(w[r] >> 32);
                pi[r] = ((u32)w[r] >> 16) & 0xFFFFu;
                const int gi = (int)(0xFFFFu ^ pi[r]);   // global point idx
                ex[r] = base[(size_t)gi * 3 + 0];
                ey[r] = base[(size_t)gi * 3 + 1];
                ez[r] = base[(size_t)gi * 3 + 2];
            }

            // tau = max over group-LAST (TOPK-th) entries. Word index is
            // lane + 64*r -> rank = (lane%TOPK + (64%TOPK)*r) % TOPK.
            u32 tl = 0;
#pragma unroll
            for (int r = 0; r < WPL; ++r) {
                const int rank = ((lane % TOPK) + (64 % TOPK) * r) % TOPK;
                if (rank == TOPK - 1) tl = pv[r] > tl ? pv[r] : tl;
            }
            const u32 tauv = wave_max_u32(tl);

            // ---- pool-FPS: exact multi-step selection + live broadcast ----
            int tc = 0;
            while (1) {
                u32 lv = 0;
#pragma unroll
                for (int r = 0; r < WPL; ++r) lv = pv[r] > lv ? pv[r] : lv;
                const u32 vmax = wave_max_u32(lv);
                // step >=2 valid only if winner VALUE strictly beats tau
                if (tc > 0 && vmax <= tauv) break;

                // per-lane best inv among entries matching vmax (0 = none)
                u32 ic = 0;
#pragma unroll
                for (int r = 0; r < WPL; ++r)
                    ic = (pv[r] == vmax && pi[r] + 1u > ic) ? pi[r] + 1u : ic;
                const u64 bal = __ballot(ic != 0);
                u32 winv; int ol;
                if (__popcll(bal) == 1) {
                    // single owner lane: local tie-break already in ic
                    ol = (int)__ffsll((long long)bal) - 1;
                    winv = __shfl(ic, ol) - 1u;
                } else {
                    // exact cross-lane tie-break: smallest global idx
                    winv = wave_max_u32(ic) - 1u;
                    int m = 0;
#pragma unroll
                    for (int r = 0; r < WPL; ++r)
                        m |= (pv[r] == vmax) & (pi[r] == winv);
                    ol = (int)__ffsll((long long)__ballot(m)) - 1;
                }

                // owner entry -> winner coords to all lanes
                float sx = 0.f, sy = 0.f, sz = 0.f;
#pragma unroll
                for (int r = 0; r < WPL; ++r) {
                    const int m = (pv[r] == vmax) & (pi[r] == winv);
                    sx = m ? ex[r] : sx;
                    sy = m ? ey[r] : sy;
                    sz = m ? ez[r] : sz;
                }
                const float wx = __shfl(sx, ol);
                const float wy = __shfl(sy, ol);
                const float wz = __shfl(sz, ol);

                // live broadcast: data, LDS-only fence, tag (NO vmcnt wait)
                if (lane == 0) {
                    wsx[tc] = wx; wsy[tc] = wy; wsz[tc] = wz;
                    asm volatile("s_waitcnt lgkmcnt(0)" ::: "memory");
                    wstag[tc] = (u32)s;
                }

                ++tc;
                if (C + tc >= MCENT || tc >= TMAX) break;

                // min-update all pool entries vs winner (bit-exact chain);
                // winner's own entry sinks to 0 automatically
#pragma unroll
                for (int r = 0; r < WPL; ++r) {
                    const float dx = __fsub_rn(ex[r], wx);
                    const float dy = __fsub_rn(ey[r], wy);
                    const float dz = __fsub_rn(ez[r], wz);
                    const float s2 = __fmaf_rn(dz, dz,
                                     __fmaf_rn(dx, dx,
                                     __fmul_rn(dy, dy)));
                    pv[r] = fbits(fminf(bitsf(pv[r]), s2));
                }
            }
            // release consumers first
            if (lane == 0) {
                asm volatile("s_waitcnt lgkmcnt(0)" ::: "memory");
                wtn = ((u32)s << 8) | (u32)tc;
            }
            // wave 0 applies winners from LDS (all tags present; same slot
            // order as consumers == R5 Phase-A chronological fminf order)
            for (int tt = 0; tt < tc; ++tt) {
                const float cx = wsx[tt], cy = wsy[tt], cz = wsz[tt];
#pragma unroll
                for (int q = 0; q < WPT; ++q) {
                    const float dx = __fsub_rn(px[q], cx);
                    const float dy = __fsub_rn(py[q], cy);
                    const float dz = __fsub_rn(pz[q], cz);
                    const float s2 = __fmaf_rn(dz, dz,
                                     __fmaf_rn(dx, dx,
                                     __fmul_rn(dy, dy)));
                    pd[q] = fminf(pd[q], s2);
                }
            }
            // batched out-writes, one winner per lane (off the hot loop)
            if (j == 0 && lane < tc) {
                float* o = out + ((size_t)b * MCENT + (C + lane)) * 3;
                o[0] = wsx[lane]; o[1] = wsy[lane]; o[2] = wsz[lane];
            }
            tn = tc;
        } else {
            // ---- sleep-consume: apply winners as they are produced ----
            int tt = 0, cnt = -1;
            while (cnt < 0 || tt < cnt) {
                if (tt < TMAX && wstag[tt] == (u32)s) {
                    const float cx = wsx[tt], cy = wsy[tt], cz = wsz[tt];
#pragma unroll
                    for (int q = 0; q < WPT; ++q) {
                        const float dx = __fsub_rn(px[q], cx);
                        const float dy = __fsub_rn(py[q], cy);
                        const float dz = __fsub_rn(pz[q], cz);
                        const float s2 = __fmaf_rn(dz, dz,
                                         __fmaf_rn(dx, dx,
                                         __fmul_rn(dy, dy)));
                        pd[q] = fminf(pd[q], s2);
                    }
                    ++tt;
                } else {
                    const u32 wd = wtn;
                    if ((wd >> 8) == (u32)s) cnt = (int)(wd & 0xFFu);
                    else __builtin_amdgcn_s_sleep(1);   // park ~64 cy
                }
            }
            tn = cnt;
        }

        C += tn;
        __syncthreads();        // single per-round barrier: aligns waves,
                                // guards LDS slot reuse for round s+1
        if (C >= MCENT) break;
    }
}

extern "C" void kernel_launch(void* const* d_in, const int* in_sizes, int n_in,
                              void* d_out, int out_size, void* d_ws, size_t ws_size,
                              hipStream_t stream) {
    const float* xyz = (const float*)d_in[0];
    float* out = (float*)d_out;
    u64* slots = (u64*)d_ws;

    // top-3 pool needs 2 parity x 32 batch x 768 words x 8 B = 384 KiB
    const size_t need3 = 2ull * NBATCH * (BPB * NGRP * 3) * sizeof(u64);
    if (ws_size >= need3) {
        fps_kernel<3><<<dim3(NBATCH * BPB), dim3(THREADS), 0, stream>>>(xyz, out, slots);
    } else {
        // TOPK=2 fallback (256 KiB)
        fps_kernel<2><<<dim3(NBATCH * BPB), dim3(THREADS), 0, stream>>>(xyz, out, slots);
    }
}